// Round 1
// baseline (392.756 us; speedup 1.0000x reference)
//
#include <hip/hip_runtime.h>

typedef unsigned short ushort_t;
typedef unsigned int   uint32;
typedef __attribute__((ext_vector_type(8))) short short8;   // 8 x bf16 (4 VGPRs)
typedef __attribute__((ext_vector_type(4))) float floatx4;  // MFMA accumulator

#define IN_F   4096
#define OUT_F  8192
#define M_TOT  512
#define NB     32            // N columns per block
#define BK     64            // K per iteration
#define WS     72            // padded W-tile row stride (elems): 144 B -> conflict-free b64/b128
#define NITER  (IN_F / BK)   // 64

__device__ __forceinline__ ushort_t f2bf(float f) {
    uint32 u = __builtin_bit_cast(uint32, f);
    u += 0x7FFFu + ((u >> 16) & 1u);    // RNE
    return (ushort_t)(u >> 16);
}

// Kernel 0: x fp32 -> bf16 into workspace (4 MB). 1024 blocks x 256 thr x 8 elems = 2M.
__global__ void cvt_x_kernel(const float* __restrict__ x, ushort_t* __restrict__ xb) {
    int i = (blockIdx.x * 256 + threadIdx.x) * 8;
    float4 v0 = *(const float4*)(x + i);
    float4 v1 = *(const float4*)(x + i + 4);
    short8 s;
    s[0] = (short)f2bf(v0.x); s[1] = (short)f2bf(v0.y);
    s[2] = (short)f2bf(v0.z); s[3] = (short)f2bf(v0.w);
    s[4] = (short)f2bf(v1.x); s[5] = (short)f2bf(v1.y);
    s[6] = (short)f2bf(v1.z); s[7] = (short)f2bf(v1.w);
    *(short8*)(xb + i) = s;
}

// Main kernel: grid 256 blocks (1/CU, LDS-capped), 512 threads = 8 waves.
// Block: out tile [512 M][32 N], full K. Wave w: rows [w*64, w*64+64).
// Indices read from HBM exactly once across the grid.
template<bool XBF16>
__global__ __launch_bounds__(512)
void ghost_kernel(const float* __restrict__ xf, const ushort_t* __restrict__ xb,
                  const int* __restrict__ base_idx, const int* __restrict__ fine_idx,
                  const float* __restrict__ scale, const float* __restrict__ lut,
                  float* __restrict__ out)
{
    __shared__ ushort_t sh_lut[65536];        // 128 KB bf16 LUT
    __shared__ ushort_t sh_w[2][NB * WS];     // 2 x 4.5 KB double-buffered W tile

    const int tid = threadIdx.x;
    const int n0  = blockIdx.x * NB;

    // ---- stage LUT as bf16 into LDS ----
    for (int i = tid * 4; i < 65536; i += 512 * 4) {
        float4 v = *(const float4*)(lut + i);
        sh_lut[i + 0] = f2bf(v.x);
        sh_lut[i + 1] = f2bf(v.y);
        sh_lut[i + 2] = f2bf(v.z);
        sh_lut[i + 3] = f2bf(v.w);
    }

    // ---- staging role: thread t handles W row sn, 4 consecutive k ----
    const int sn  = tid >> 4;          // 0..31
    const int skq = (tid & 15) * 4;    // 0,4,...,60
    const int* bp = base_idx + (size_t)(n0 + sn) * IN_F + skq;
    const int* fp = fine_idx + (size_t)(n0 + sn) * IN_F + skq;

    __syncthreads();   // LUT ready before any gather

    // prologue: stage W(0) into buf0, prefetch idx(1)
    int4 pb = *(const int4*)(bp);
    int4 pf = *(const int4*)(fp);
    {
        uint32 w0 = (uint32)sh_lut[(pb.x << 8) + pf.x] | ((uint32)sh_lut[(pb.y << 8) + pf.y] << 16);
        uint32 w1 = (uint32)sh_lut[(pb.z << 8) + pf.z] | ((uint32)sh_lut[(pb.w << 8) + pf.w] << 16);
        uint2 wv; wv.x = w0; wv.y = w1;
        *(uint2*)&sh_w[0][sn * WS + skq] = wv;
    }
    pb = *(const int4*)(bp + BK);
    pf = *(const int4*)(fp + BK);
    __syncthreads();   // W(0) visible

    // ---- MFMA role ----
    const int lane = tid & 63;
    const int wave = tid >> 6;      // 0..7
    const int l16  = lane & 15;
    const int quad = lane >> 4;     // 0..3
    const int mrow = wave * 64 + l16;

    floatx4 acc[4][2];
    const floatx4 zero = {0.f, 0.f, 0.f, 0.f};
#pragma unroll
    for (int f = 0; f < 4; ++f) { acc[f][0] = zero; acc[f][1] = zero; }

    const ushort_t* xrow  = XBF16 ? (xb + (size_t)mrow * IN_F + quad * 8) : (const ushort_t*)nullptr;
    const float*    xrowf = XBF16 ? (const float*)nullptr : (xf + (size_t)mrow * IN_F + quad * 8);

    for (int t = 0; t < NITER; ++t) {
        const int k0 = t * BK;

        // stage W(t+1) into buf (t+1)&1 (regs hold idx(t+1); t=63 re-stage is benign)
        {
            uint32 w0 = (uint32)sh_lut[(pb.x << 8) + pf.x] | ((uint32)sh_lut[(pb.y << 8) + pf.y] << 16);
            uint32 w1 = (uint32)sh_lut[(pb.z << 8) + pf.z] | ((uint32)sh_lut[(pb.w << 8) + pf.w] << 16);
            uint2 wv; wv.x = w0; wv.y = w1;
            *(uint2*)&sh_w[(t + 1) & 1][sn * WS + skq] = wv;
        }
        // prefetch idx(t+2) (clamped; covers latency across the barrier)
        {
            const int kk = (t + 2 < NITER ? t + 2 : NITER - 1) * BK;
            pb = *(const int4*)(bp + kk);
            pf = *(const int4*)(fp + kk);
        }

        // MFMA(t) from buf t&1
        const ushort_t* wb = sh_w[t & 1];
#pragma unroll
        for (int ks = 0; ks < 2; ++ks) {
            const int kk = k0 + ks * 32;
            short8 b0 = *(const short8*)&wb[l16        * WS + ks * 32 + quad * 8];
            short8 b1 = *(const short8*)&wb[(16 + l16) * WS + ks * 32 + quad * 8];
#pragma unroll
            for (int f = 0; f < 4; ++f) {
                short8 a;
                if (XBF16) {
                    a = *(const short8*)(xrow + (size_t)f * 16 * IN_F + kk);
                } else {
                    const float* p = xrowf + (size_t)f * 16 * IN_F + kk;
                    float4 u0 = *(const float4*)p;
                    float4 u1 = *(const float4*)(p + 4);
                    a[0] = (short)f2bf(u0.x); a[1] = (short)f2bf(u0.y);
                    a[2] = (short)f2bf(u0.z); a[3] = (short)f2bf(u0.w);
                    a[4] = (short)f2bf(u1.x); a[5] = (short)f2bf(u1.y);
                    a[6] = (short)f2bf(u1.z); a[7] = (short)f2bf(u1.w);
                }
                acc[f][0] = __builtin_amdgcn_mfma_f32_16x16x32_bf16(a, b0, acc[f][0], 0, 0, 0);
                acc[f][1] = __builtin_amdgcn_mfma_f32_16x16x32_bf16(a, b1, acc[f][1], 0, 0, 0);
            }
        }
        __syncthreads();   // W(t+1) visible; buf t&1 free for iter t+1's staging
    }

    // ---- epilogue: C/D 16x16x32 mapping col=lane&15, row=quad*4+reg ----
#pragma unroll
    for (int nf = 0; nf < 2; ++nf) {
        const int col = n0 + nf * 16 + l16;
        const float sc = scale[col];
#pragma unroll
        for (int f = 0; f < 4; ++f) {
            const int r0 = wave * 64 + f * 16 + quad * 4;
#pragma unroll
            for (int r = 0; r < 4; ++r) {
                out[(size_t)(r0 + r) * OUT_F + col] = acc[f][nf][r] * sc;
            }
        }
    }
}

extern "C" void kernel_launch(void* const* d_in, const int* in_sizes, int n_in,
                              void* d_out, int out_size, void* d_ws, size_t ws_size,
                              hipStream_t stream) {
    const float* x      = (const float*)d_in[0];
    const int*   bidx   = (const int*)d_in[1];
    const int*   fidx   = (const int*)d_in[2];
    const float* scale  = (const float*)d_in[3];
    const float* lut    = (const float*)d_in[4];
    float*       out    = (float*)d_out;

    const size_t xb_bytes = (size_t)M_TOT * IN_F * sizeof(ushort_t);  // 4 MB
    if (ws_size >= xb_bytes) {
        ushort_t* xb = (ushort_t*)d_ws;
        cvt_x_kernel<<<1024, 256, 0, stream>>>(x, xb);
        ghost_kernel<true><<<OUT_F / NB, 512, 0, stream>>>(x, xb, bidx, fidx, scale, lut, out);
    } else {
        ghost_kernel<false><<<OUT_F / NB, 512, 0, stream>>>(x, nullptr, bidx, fidx, scale, lut, out);
    }
}

// Round 2
// 382.997 us; speedup vs baseline: 1.0255x; 1.0255x over previous
//
#include <hip/hip_runtime.h>

typedef unsigned short ushort_t;
typedef unsigned int   uint32;
typedef __attribute__((ext_vector_type(8))) short short8;   // 8 x bf16 (4 VGPRs)
typedef __attribute__((ext_vector_type(4))) float floatx4;  // MFMA accumulator

#define IN_F   4096
#define OUT_F  8192
#define M_TOT  512
#define NB     32            // N columns per block
#define BK     128           // K per iteration
#define WS     136           // padded W-tile row stride (elems): 272 B -> uniform bank touches
#define NITER  (IN_F / BK)   // 32

__device__ __forceinline__ ushort_t f2bf(float f) {
    uint32 u = __builtin_bit_cast(uint32, f);
    u += 0x7FFFu + ((u >> 16) & 1u);    // RNE
    return (ushort_t)(u >> 16);
}

// Kernel 0: x fp32 -> bf16 into workspace (4 MB). 1024 blocks x 256 thr x 8 elems = 2M.
__global__ void cvt_x_kernel(const float* __restrict__ x, ushort_t* __restrict__ xb) {
    int i = (blockIdx.x * 256 + threadIdx.x) * 8;
    float4 v0 = *(const float4*)(x + i);
    float4 v1 = *(const float4*)(x + i + 4);
    short8 s;
    s[0] = (short)f2bf(v0.x); s[1] = (short)f2bf(v0.y);
    s[2] = (short)f2bf(v0.z); s[3] = (short)f2bf(v0.w);
    s[4] = (short)f2bf(v1.x); s[5] = (short)f2bf(v1.y);
    s[6] = (short)f2bf(v1.z); s[7] = (short)f2bf(v1.w);
    *(short8*)(xb + i) = s;
}

// Main kernel: grid 256 blocks (1/CU, LDS-capped by the 128KB LUT), 1024 threads = 16 waves.
// Block: out tile [512 M][32 N], full K. Wave w owns M rows [w*32, w*32+32).
// Indices are read from HBM/L3 exactly once across the grid.
template<bool XBF16>
__global__ __launch_bounds__(1024, 4)
void ghost_kernel(const float* __restrict__ xf, const ushort_t* __restrict__ xb,
                  const int* __restrict__ base_idx, const int* __restrict__ fine_idx,
                  const float* __restrict__ scale, const float* __restrict__ lut,
                  float* __restrict__ out)
{
    __shared__ ushort_t sh_lut[65536];        // 128 KB bf16 LUT
    __shared__ ushort_t sh_w[2][NB * WS];     // 2 x 8.5 KB double-buffered W tile

    const int tid = threadIdx.x;
    const int n0  = blockIdx.x * NB;

    // ---- stage LUT as bf16 into LDS ----
    for (int i = tid * 4; i < 65536; i += 1024 * 4) {
        float4 v = *(const float4*)(lut + i);
        sh_lut[i + 0] = f2bf(v.x);
        sh_lut[i + 1] = f2bf(v.y);
        sh_lut[i + 2] = f2bf(v.z);
        sh_lut[i + 3] = f2bf(v.w);
    }

    // ---- staging role: thread t handles W row sn, 4 consecutive k ----
    const int sn  = tid >> 5;          // 0..31
    const int skq = (tid & 31) * 4;    // 0,4,...,124
    const int* bp = base_idx + (size_t)(n0 + sn) * IN_F + skq;
    const int* fp = fine_idx + (size_t)(n0 + sn) * IN_F + skq;

    __syncthreads();   // LUT ready before any gather

    // prologue: stage W(0) into buf0, prefetch idx(1)
    int4 pb = *(const int4*)(bp);
    int4 pf = *(const int4*)(fp);
    {
        uint32 w0 = (uint32)sh_lut[(pb.x << 8) + pf.x] | ((uint32)sh_lut[(pb.y << 8) + pf.y] << 16);
        uint32 w1 = (uint32)sh_lut[(pb.z << 8) + pf.z] | ((uint32)sh_lut[(pb.w << 8) + pf.w] << 16);
        uint2 wv; wv.x = w0; wv.y = w1;
        *(uint2*)&sh_w[0][sn * WS + skq] = wv;
    }
    pb = *(const int4*)(bp + BK);
    pf = *(const int4*)(fp + BK);
    __syncthreads();   // W(0) visible

    // ---- MFMA role ----
    const int lane = tid & 63;
    const int wave = tid >> 6;      // 0..15
    const int l16  = lane & 15;
    const int quad = lane >> 4;     // 0..3

    floatx4 acc[2][2];
    const floatx4 zero = {0.f, 0.f, 0.f, 0.f};
    acc[0][0] = zero; acc[0][1] = zero; acc[1][0] = zero; acc[1][1] = zero;

    const int mrow = wave * 32 + l16;
    const ushort_t* xrow  = XBF16 ? (xb + (size_t)mrow * IN_F + quad * 8) : (const ushort_t*)nullptr;
    const float*    xrowf = XBF16 ? (const float*)nullptr : (xf + (size_t)mrow * IN_F + quad * 8);

    for (int t = 0; t < NITER; ++t) {
        const int k0 = t * BK;

        // stage W(t+1) into buf (t+1)&1 (regs hold idx(t+1); t=NITER-1 re-stage is benign)
        {
            uint32 w0 = (uint32)sh_lut[(pb.x << 8) + pf.x] | ((uint32)sh_lut[(pb.y << 8) + pf.y] << 16);
            uint32 w1 = (uint32)sh_lut[(pb.z << 8) + pf.z] | ((uint32)sh_lut[(pb.w << 8) + pf.w] << 16);
            uint2 wv; wv.x = w0; wv.y = w1;
            *(uint2*)&sh_w[(t + 1) & 1][sn * WS + skq] = wv;
        }
        // prefetch idx(t+2) (clamped; distance beyond the barrier drain is free to issue)
        {
            const int kk = (t + 2 < NITER ? t + 2 : NITER - 1) * BK;
            pb = *(const int4*)(bp + kk);
            pf = *(const int4*)(fp + kk);
        }

        // MFMA(t) from buf t&1: 4 ks x 2 f x 2 n = 16 MFMAs per wave
        const ushort_t* wb = sh_w[t & 1];
#pragma unroll
        for (int ks = 0; ks < 4; ++ks) {
            const int kk = k0 + ks * 32;
            short8 b0 = *(const short8*)&wb[l16        * WS + ks * 32 + quad * 8];
            short8 b1 = *(const short8*)&wb[(16 + l16) * WS + ks * 32 + quad * 8];
            short8 a0, a1;
            if (XBF16) {
                a0 = *(const short8*)(xrow + kk);
                a1 = *(const short8*)(xrow + (size_t)16 * IN_F + kk);
            } else {
                const float* p0 = xrowf + kk;
                const float* p1 = xrowf + (size_t)16 * IN_F + kk;
                float4 u0 = *(const float4*)p0, u1 = *(const float4*)(p0 + 4);
                float4 v0 = *(const float4*)p1, v1 = *(const float4*)(p1 + 4);
                a0[0] = (short)f2bf(u0.x); a0[1] = (short)f2bf(u0.y);
                a0[2] = (short)f2bf(u0.z); a0[3] = (short)f2bf(u0.w);
                a0[4] = (short)f2bf(u1.x); a0[5] = (short)f2bf(u1.y);
                a0[6] = (short)f2bf(u1.z); a0[7] = (short)f2bf(u1.w);
                a1[0] = (short)f2bf(v0.x); a1[1] = (short)f2bf(v0.y);
                a1[2] = (short)f2bf(v0.z); a1[3] = (short)f2bf(v0.w);
                a1[4] = (short)f2bf(v1.x); a1[5] = (short)f2bf(v1.y);
                a1[6] = (short)f2bf(v1.z); a1[7] = (short)f2bf(v1.w);
            }
            acc[0][0] = __builtin_amdgcn_mfma_f32_16x16x32_bf16(a0, b0, acc[0][0], 0, 0, 0);
            acc[0][1] = __builtin_amdgcn_mfma_f32_16x16x32_bf16(a0, b1, acc[0][1], 0, 0, 0);
            acc[1][0] = __builtin_amdgcn_mfma_f32_16x16x32_bf16(a1, b0, acc[1][0], 0, 0, 0);
            acc[1][1] = __builtin_amdgcn_mfma_f32_16x16x32_bf16(a1, b1, acc[1][1], 0, 0, 0);
        }
        __syncthreads();   // W(t+1) visible; buf t&1 free for iter t+1's staging
    }

    // ---- epilogue: C/D 16x16x32 mapping col=lane&15, row=quad*4+reg ----
#pragma unroll
    for (int nf = 0; nf < 2; ++nf) {
        const int col = n0 + nf * 16 + l16;
        const float sc = scale[col];
#pragma unroll
        for (int f = 0; f < 2; ++f) {
            const int r0 = wave * 32 + f * 16 + quad * 4;
#pragma unroll
            for (int r = 0; r < 4; ++r) {
                out[(size_t)(r0 + r) * OUT_F + col] = acc[f][nf][r] * sc;
            }
        }
    }
}

extern "C" void kernel_launch(void* const* d_in, const int* in_sizes, int n_in,
                              void* d_out, int out_size, void* d_ws, size_t ws_size,
                              hipStream_t stream) {
    const float* x      = (const float*)d_in[0];
    const int*   bidx   = (const int*)d_in[1];
    const int*   fidx   = (const int*)d_in[2];
    const float* scale  = (const float*)d_in[3];
    const float* lut    = (const float*)d_in[4];
    float*       out    = (float*)d_out;

    const size_t xb_bytes = (size_t)M_TOT * IN_F * sizeof(ushort_t);  // 4 MB
    if (ws_size >= xb_bytes) {
        ushort_t* xb = (ushort_t*)d_ws;
        cvt_x_kernel<<<1024, 256, 0, stream>>>(x, xb);
        ghost_kernel<true><<<OUT_F / NB, 1024, 0, stream>>>(x, xb, bidx, fidx, scale, lut, out);
    } else {
        ghost_kernel<false><<<OUT_F / NB, 1024, 0, stream>>>(x, nullptr, bidx, fidx, scale, lut, out);
    }
}